// Round 3
// baseline (293.008 us; speedup 1.0000x reference)
//
#include <hip/hip_runtime.h>

// TemporalLogicLayer R3: persistent-weights MFMA kernel.
// out[b,t,o] = max_{s>=t} sigmoid(5*(relu(relu([cummax(P[t..s])|P[s]]W1+b1)W2+b2)W3+b3))
//
// - PW[s*32+b][n] = P[b,s,:] @ W1[128:,:] precomputed (t-invariant) -> L1 K=128.
// - cummax prefix [t,s0) answered O(1) from a 5-level sparse max table (f16;
//   max commutes with monotone RNE f32->f16 cvt, so identical to f16 pipeline).
// - main kernel: 256 blocks (1/CU, 161KB dynamic LDS), 512 thr = 8 waves.
//   Weights W1/W2 staged to LDS once per block; item loop over 2112 (t, s-chunk
//   of 4) work units, ~8.25/block (balanced). Per item: stage cmx (M=128 rows)
//   -> L1 -> L2 -> L3, 4 barriers.
// - all layers TRANSPOSED (W = A-operand, activations = B-operand): C-frag lane
//   holds 4 consecutive FEATURES at one batch-row -> b64 row-major h stores,
//   which is exactly the next layer's B-fragment read layout.
// - K=128 LDS buffers XOR-swizzled (16B blocks, blk ^ (row&15)); K=160 buffers
//   padded to stride 168 f16 (dw-stride 84 == 4 mod 8 -> uniform banks).
// - h cols 144..159 zeroed once per block (W2t/W3t rows there are zero, but
//   LDS garbage could be NaN; 0*0 is safe).

#define TT 128
#define BB 32
#define DD 128
#define OO 64
#define NP 144
#define HSTR 168
#define N_ITEMS 2112

typedef __attribute__((ext_vector_type(8))) _Float16 half8;
typedef __attribute__((ext_vector_type(4))) _Float16 half4;
typedef __attribute__((ext_vector_type(4))) float f32x4;

// ws layout (bytes)
#define W1T_OFF 0                                   // f16 [144][256]
#define W2T_OFF (W1T_OFF + 144*256*2)               // f16 [144][160]
#define W3T_OFF (W2T_OFF + 144*160*2)               // f16 [64][160]
#define B1P_OFF (W3T_OFF + 64*160*2)                // f32 [144]
#define B2P_OFF (B1P_OFF + 144*4)                   // f32 [144]
#define PW_OFF  (B2P_OFF + 144*4)                   // f16 [4096][144]
#define TAB_OFF (PW_OFF + 4096*144*2)               // f16 [5][128][32][128]

#define MFMA(A, B, C) __builtin_amdgcn_mfma_f32_16x16x32_f16((A), (B), (C), 0, 0, 0)

__device__ __forceinline__ half8 h8max(half8 a, half8 b) {
    half8 r;
    #pragma unroll
    for (int i = 0; i < 8; ++i) r[i] = (a[i] > b[i]) ? a[i] : b[i];
    return r;
}

// ---------- prep 1: weights -> transposed padded f16 ----------
__global__ void tll_prep_w(const float* __restrict__ W1, const float* __restrict__ b1,
                           const float* __restrict__ W2, const float* __restrict__ b2,
                           const float* __restrict__ W3, char* __restrict__ ws) {
    _Float16* W1t = (_Float16*)(ws + W1T_OFF);
    _Float16* W2t = (_Float16*)(ws + W2T_OFF);
    _Float16* W3t = (_Float16*)(ws + W3T_OFF);
    float*    b1p = (float*)(ws + B1P_OFF);
    float*    b2p = (float*)(ws + B2P_OFF);
    int idx = blockIdx.x * 256 + threadIdx.x;       // 144 blocks
    if (idx < 144*256) {                            // W1t[n][k] = W1[k][n]
        int n = idx >> 8, k = idx & 255;
        W1t[idx] = (_Float16)((n < 132) ? W1[k*132 + n] : 0.f);
    }
    if (idx < 144*160) {                            // W2t[n][k] = W2[k][n]
        int n = idx / 160, k = idx - n*160;
        W2t[idx] = (_Float16)((n < 132 && k < 132) ? W2[k*132 + n] : 0.f);
    }
    if (idx < 64*160) {                             // W3t[o][k] = W3[k][o]
        int o = idx / 160, k = idx - o*160;
        W3t[idx] = (_Float16)((k < 132) ? W3[k*64 + o] : 0.f);
    }
    if (idx < 144) {
        b1p[idx] = (idx < 132) ? b1[idx] : 0.f;
        b2p[idx] = (idx < 132) ? b2[idx] : 0.f;
    }
}

// ---------- prep 2: PW[row][n] = P[row] @ W1[128:256,:]  (row = s*32+b) ----
__global__ void tll_prep_pw(const float* __restrict__ P, char* __restrict__ ws) {
    const _Float16* W1t = (const _Float16*)(ws + W1T_OFF);
    _Float16* PW = (_Float16*)(ws + PW_OFF);
    const int tid = threadIdx.x, w = tid >> 6, lane = tid & 63;
    const int ln = lane & 15, q = lane >> 4;

    // this wave: 4 batch-row tiles (B-operand), all 9 feature tiles (A)
    half8 Bf[4][4];
    int rows[4];
    #pragma unroll
    for (int nj = 0; nj < 4; ++nj) {
        int row = (blockIdx.x*16 + w*4 + nj)*16 + ln;      // 0..4095
        rows[nj] = row;
        int b_ = row & 31, s_ = row >> 5;
        const float* pp = P + b_*(TT*DD) + s_*DD;
        #pragma unroll
        for (int kst = 0; kst < 4; ++kst) {
            f32x4 p0 = *(const f32x4*)(pp + kst*32 + q*8);
            f32x4 p1 = *(const f32x4*)(pp + kst*32 + q*8 + 4);
            half8 h;
            #pragma unroll
            for (int i = 0; i < 4; ++i) { h[i] = (_Float16)p0[i]; h[4+i] = (_Float16)p1[i]; }
            Bf[nj][kst] = h;
        }
    }
    for (int mt = 0; mt < 9; ++mt) {
        f32x4 acc[4];
        #pragma unroll
        for (int nj = 0; nj < 4; ++nj) acc[nj] = (f32x4){0.f,0.f,0.f,0.f};
        #pragma unroll
        for (int kst = 0; kst < 4; ++kst) {
            half8 A = *(const half8*)(W1t + (mt*16+ln)*256 + 128 + kst*32 + q*8);
            #pragma unroll
            for (int nj = 0; nj < 4; ++nj) acc[nj] = MFMA(A, Bf[nj][kst], acc[nj]);
        }
        #pragma unroll
        for (int nj = 0; nj < 4; ++nj) {
            half4 hv;
            #pragma unroll
            for (int i = 0; i < 4; ++i) hv[i] = (_Float16)acc[nj][i];
            *(half4*)(PW + (size_t)rows[nj]*NP + mt*16 + q*4) = hv;
        }
    }
}

// ---------- prep 3: sparse max table, levels 2^2..2^6 ----------
__global__ void tll_prep_tab(const float* __restrict__ P, char* __restrict__ ws) {
    extern __shared__ _Float16 sm[];                 // 2 x 128*128 f16 = 64 KB
    _Float16* buf0 = sm;
    _Float16* buf1 = sm + 128*128;
    _Float16* TAB = (_Float16*)(ws + TAB_OFF);
    const int b = blockIdx.x, tid = threadIdx.x;

    for (int i = tid; i < 4096; i += 256) {          // P[b] -> f16 buf0
        f32x4 v = ((const f32x4*)(P + b*(TT*DD)))[i];
        half4 h;
        #pragma unroll
        for (int j = 0; j < 4; ++j) h[j] = (_Float16)v[j];
        *(half4*)(buf0 + i*4) = h;
    }
    __syncthreads();
    // level 0 (len 4) from buf0
    for (int cell = tid; cell < 16384; cell += 256) {
        int t = cell >> 7, d = cell & 127;
        _Float16 v = buf0[t*128 + d];
        #pragma unroll
        for (int dt = 1; dt < 4; ++dt) {
            int s = t + dt; if (s > 127) s = 127;
            _Float16 u = buf0[s*128 + d];
            v = (u > v) ? u : v;
        }
        buf1[cell] = v;
        TAB[(size_t)0*524288 + t*4096 + b*128 + d] = v;
    }
    __syncthreads();
    // levels 1..4: shift 4,8,16,32; ping-pong buf1<->buf0
    _Float16* src = buf1; _Float16* dst = buf0;
    #pragma unroll
    for (int lev = 1; lev < 5; ++lev) {
        int shift = 2 << lev;                        // 4,8,16,32 -> wait: lev1->8? no: 2<<1=4
        shift = 1 << (lev + 1);                      // lev1: 4, lev2: 8, lev3: 16, lev4: 32
        for (int cell = tid; cell < 16384; cell += 256) {
            int t = cell >> 7, d = cell & 127;
            int s = t + shift; if (s > 127) s = 127;
            _Float16 a = src[t*128 + d], c = src[s*128 + d];
            _Float16 v = (c > a) ? c : a;
            dst[cell] = v;
            TAB[(size_t)lev*524288 + t*4096 + b*128 + d] = v;
        }
        __syncthreads();
        _Float16* tmp = src; src = dst; dst = tmp;
    }
}

// ---------- main ----------
__global__ __launch_bounds__(512, 2) void tll_main(
    const float* __restrict__ P, const float* __restrict__ b3,
    const char* __restrict__ ws, unsigned int* __restrict__ outU)
{
    extern __shared__ char smem[];
    _Float16* W1s = (_Float16*)smem;                 // [144][128] swizzled
    _Float16* W2s = W1s + 144*128;                   // [144][168]
    _Float16* hS  = W2s + 144*HSTR;                  // [128][168]
    _Float16* cmx = hS  + 128*HSTR;                  // [128][128] swizzled

    const _Float16* W1t = (const _Float16*)(ws + W1T_OFF);
    const _Float16* W2t = (const _Float16*)(ws + W2T_OFF);
    const _Float16* W3t = (const _Float16*)(ws + W3T_OFF);
    const float*    b1p = (const float*)(ws + B1P_OFF);
    const float*    b2p = (const float*)(ws + B2P_OFF);
    const _Float16* PW  = (const _Float16*)(ws + PW_OFF);
    const _Float16* TAB = (const _Float16*)(ws + TAB_OFF);

    const int tid = threadIdx.x, w = tid >> 6, lane = tid & 63;
    const int ln = lane & 15, q = lane >> 4;
    const int fg = w >> 1, rg = w & 1;               // L1/L2: 4 f-groups x 2 r-groups
    const bool has3 = (fg == 0);                     // f-tiles: (3,2,2,2) of 9
    const int fb = (fg == 0) ? 0 : (16 + 32*fg);     // 0,48,80,112
    const int f0A = fb, f0B = fb + 16, f0C = fb + 32;
    const int og = fg, rg3 = rg;                     // L3: 4 o-tiles x 2 r-groups

    // ---- stage weights to LDS (once) ----
    for (int idx = tid; idx < 144*16; idx += 512) {  // W1 swizzled
        int n = idx >> 4, kb = idx & 15;
        *(half8*)(W1s + n*128 + ((kb ^ (n & 15))*8)) =
            *(const half8*)(W1t + n*256 + kb*8);
    }
    for (int idx = tid; idx < 144*20; idx += 512) {  // W2 padded stride
        int n = idx / 20, kb = idx - n*20;
        *(half8*)(W2s + n*HSTR + kb*8) = *(const half8*)(W2t + n*160 + kb*8);
    }
    for (int idx = tid; idx < 256; idx += 512) {     // zero h cols 144..159
        int row = idx >> 1, hv = idx & 1;
        half8 z;
        #pragma unroll
        for (int i = 0; i < 8; ++i) z[i] = (_Float16)0.f;
        *(half8*)(hS + row*HSTR + 144 + hv*8) = z;
    }

    // per-lane constant biases
    const f32x4 biasA1 = *(const f32x4*)(b1p + f0A + q*4);
    const f32x4 biasB1 = *(const f32x4*)(b1p + f0B + q*4);
    const f32x4 biasC1 = has3 ? *(const f32x4*)(b1p + f0C + q*4) : (f32x4){0,0,0,0};
    const f32x4 biasA2 = *(const f32x4*)(b2p + f0A + q*4);
    const f32x4 biasB2 = *(const f32x4*)(b2p + f0B + q*4);
    const f32x4 biasC2 = has3 ? *(const f32x4*)(b2p + f0C + q*4) : (f32x4){0,0,0,0};
    const f32x4 bias3  = *(const f32x4*)(b3 + og*16 + q*4);

    const int sb = tid >> 4, dblk = tid & 15, d0 = dblk*8;  // staging role
    __syncthreads();

    for (int it = blockIdx.x; it < N_ITEMS; it += 256) {
        // ---- decode item -> (t, c) ----
        int g = (int)((65.0f - sqrtf((float)(4225 - 2*it))) * 0.5f);
        if (g < 0) g = 0; if (g > 31) g = 31;
        while (g > 0 && 2*g*(65 - g) > it) --g;
        while (2*(g+1)*(65 - (g+1)) <= it) ++g;
        int rem = it - 2*g*(65 - g);
        int ntc = 32 - g;
        int t  = 4*g + rem/ntc;
        int c  = rem - (rem/ntc)*ntc;
        int s0 = t + 4*c;

        // ---- stage cmx: init from table, fold 4 steps ----
        {
            half8 mi;
            if (c == 0) {
                #pragma unroll
                for (int i = 0; i < 8; ++i) mi[i] = (_Float16)(-65504.0f);
            } else {
                int L = 4*c;
                int klev = 31 - __builtin_clz(L);
                int t2 = s0 - (1 << klev);
                const _Float16* tb = TAB + (size_t)(klev - 2)*524288;
                half8 x = *(const half8*)(tb + t*4096 + sb*128 + d0);
                half8 y = *(const half8*)(tb + t2*4096 + sb*128 + d0);
                mi = h8max(x, y);
            }
            const float* pb = P + sb*(TT*DD) + d0;
            #pragma unroll
            for (int j = 0; j < 4; ++j) {
                int s = s0 + j; if (s > 127) s = 127;
                f32x4 p0 = *(const f32x4*)(pb + s*DD);
                f32x4 p1 = *(const f32x4*)(pb + s*DD + 4);
                half8 ph;
                #pragma unroll
                for (int i = 0; i < 4; ++i) { ph[i] = (_Float16)p0[i]; ph[4+i] = (_Float16)p1[i]; }
                mi = h8max(mi, ph);
                int row = j*32 + sb;
                *(half8*)(cmx + row*128 + ((dblk ^ (row & 15))*8)) = mi;
            }
        }
        __syncthreads();                             // [A]

        // ---- L1': z1^T = W1a^T @ cmx^T, init = PW + b1, relu -> hS ----
        {
            f32x4 aA[4], aB[4], aC[4];
            #pragma unroll
            for (int rj = 0; rj < 4; ++rj) {
                int rowg = s0*32 + (rg*4 + rj)*16 + ln;
                if (rowg > 4095) rowg = 4095;
                const _Float16* pwp = PW + (size_t)rowg*NP;
                half4 pA = *(const half4*)(pwp + f0A + q*4);
                half4 pB = *(const half4*)(pwp + f0B + q*4);
                aA[rj] = biasA1; aB[rj] = biasB1;
                #pragma unroll
                for (int i = 0; i < 4; ++i) { aA[rj][i] += (float)pA[i]; aB[rj][i] += (float)pB[i]; }
                if (has3) {
                    half4 pC = *(const half4*)(pwp + f0C + q*4);
                    aC[rj] = biasC1;
                    #pragma unroll
                    for (int i = 0; i < 4; ++i) aC[rj][i] += (float)pC[i];
                }
            }
            #pragma unroll
            for (int kst = 0; kst < 4; ++kst) {
                int kb = kst*4 + q;
                half8 wA = *(const half8*)(W1s + (f0A+ln)*128 + ((kb ^ ln)*8));
                half8 wB = *(const half8*)(W1s + (f0B+ln)*128 + ((kb ^ ln)*8));
                half8 wC;
                if (has3) wC = *(const half8*)(W1s + (f0C+ln)*128 + ((kb ^ ln)*8));
                #pragma unroll
                for (int rj = 0; rj < 4; ++rj) {
                    int row = (rg*4 + rj)*16 + ln;
                    half8 bf = *(const half8*)(cmx + row*128 + ((kb ^ (row & 15))*8));
                    aA[rj] = MFMA(wA, bf, aA[rj]);
                    aB[rj] = MFMA(wB, bf, aB[rj]);
                    if (has3) aC[rj] = MFMA(wC, bf, aC[rj]);
                }
            }
            #pragma unroll
            for (int rj = 0; rj < 4; ++rj) {
                int row = (rg*4 + rj)*16 + ln;
                half4 hA, hB, hC;
                #pragma unroll
                for (int i = 0; i < 4; ++i) {
                    hA[i] = (_Float16)fmaxf(aA[rj][i], 0.f);
                    hB[i] = (_Float16)fmaxf(aB[rj][i], 0.f);
                }
                *(half4*)(hS + row*HSTR + f0A + q*4) = hA;
                *(half4*)(hS + row*HSTR + f0B + q*4) = hB;
                if (has3) {
                    #pragma unroll
                    for (int i = 0; i < 4; ++i) hC[i] = (_Float16)fmaxf(aC[rj][i], 0.f);
                    *(half4*)(hS + row*HSTR + f0C + q*4) = hC;
                }
            }
        }
        __syncthreads();                             // [B]

        // ---- L2': z2^T = W2^T @ h1^T, relu (held in regs until [C]) ----
        half4 h2A[4], h2B[4], h2C[4];
        {
            f32x4 aA[4], aB[4], aC[4];
            #pragma unroll
            for (int rj = 0; rj < 4; ++rj) { aA[rj] = biasA2; aB[rj] = biasB2; if (has3) aC[rj] = biasC2; }
            #pragma unroll
            for (int kst = 0; kst < 5; ++kst) {
                half8 wA = *(const half8*)(W2s + (f0A+ln)*HSTR + kst*32 + q*8);
                half8 wB = *(const half8*)(W2s + (f0B+ln)*HSTR + kst*32 + q*8);
                half8 wC;
                if (has3) wC = *(const half8*)(W2s + (f0C+ln)*HSTR + kst*32 + q*8);
                #pragma unroll
                for (int rj = 0; rj < 4; ++rj) {
                    int row = (rg*4 + rj)*16 + ln;
                    half8 bf = *(const half8*)(hS + row*HSTR + kst*32 + q*8);
                    aA[rj] = MFMA(wA, bf, aA[rj]);
                    aB[rj] = MFMA(wB, bf, aB[rj]);
                    if (has3) aC[rj] = MFMA(wC, bf, aC[rj]);
                }
            }
            #pragma unroll
            for (int rj = 0; rj < 4; ++rj) {
                #pragma unroll
                for (int i = 0; i < 4; ++i) {
                    h2A[rj][i] = (_Float16)fmaxf(aA[rj][i], 0.f);
                    h2B[rj][i] = (_Float16)fmaxf(aB[rj][i], 0.f);
                    if (has3) h2C[rj][i] = (_Float16)fmaxf(aC[rj][i], 0.f);
                }
            }
        }
        __syncthreads();                             // [C] all h1 reads done
        #pragma unroll
        for (int rj = 0; rj < 4; ++rj) {
            int row = (rg*4 + rj)*16 + ln;
            *(half4*)(hS + row*HSTR + f0A + q*4) = h2A[rj];
            *(half4*)(hS + row*HSTR + f0B + q*4) = h2B[rj];
            if (has3) *(half4*)(hS + row*HSTR + f0C + q*4) = h2C[rj];
        }
        __syncthreads();                             // [D]

        // ---- L3': z3^T = W3^T @ h2^T (W3 from global), reduce, atomics ----
        {
            f32x4 z[4];
            #pragma unroll
            for (int rj = 0; rj < 4; ++rj) z[rj] = bias3;
            #pragma unroll
            for (int kst = 0; kst < 5; ++kst) {
                half8 wO = *(const half8*)(W3t + (og*16+ln)*160 + kst*32 + q*8);
                #pragma unroll
                for (int rj = 0; rj < 4; ++rj) {
                    int row = (rg3*4 + rj)*16 + ln;
                    half8 bf = *(const half8*)(hS + row*HSTR + kst*32 + q*8);
                    z[rj] = MFMA(wO, bf, z[rj]);
                }
            }
            // Rt = rg3*4+rj: j = Rt>>1, bgroup = Rt&1; valid j iff s0+j < 128
            bool v0 = (s0 + rg3*2) < TT;
            bool v1 = (s0 + rg3*2 + 1) < TT;
            if (v0) {
                f32x4 zA = z[0], zB = z[1];
                if (v1) {
                    #pragma unroll
                    for (int i = 0; i < 4; ++i) {
                        zA[i] = fmaxf(zA[i], z[2][i]);
                        zB[i] = fmaxf(zB[i], z[3][i]);
                    }
                }
                #pragma unroll
                for (int i = 0; i < 4; ++i) {
                    float yA = 1.f / (1.f + __expf(-5.f * zA[i]));
                    float yB = 1.f / (1.f + __expf(-5.f * zB[i]));
                    int o = og*16 + q*4 + i;
                    atomicMax(&outU[(size_t)ln*(TT*OO) + t*OO + o], __float_as_uint(yA));
                    atomicMax(&outU[(size_t)(16+ln)*(TT*OO) + t*OO + o], __float_as_uint(yB));
                }
            }
        }
        __syncthreads();                             // protect hS/cmx for next item
    }
}

extern "C" void kernel_launch(void* const* d_in, const int* in_sizes, int n_in,
                              void* d_out, int out_size, void* d_ws, size_t ws_size,
                              hipStream_t stream) {
    const float* P  = (const float*)d_in[0];
    const float* W1 = (const float*)d_in[1];
    const float* b1 = (const float*)d_in[2];
    const float* W2 = (const float*)d_in[3];
    const float* b2 = (const float*)d_in[4];
    const float* W3 = (const float*)d_in[5];
    const float* b3 = (const float*)d_in[6];

    tll_prep_w<<<144, 256, 0, stream>>>(W1, b1, W2, b2, W3, (char*)d_ws);
    tll_prep_pw<<<16, 256, 0, stream>>>(P, (char*)d_ws);
    tll_prep_tab<<<32, 256, 65536, stream>>>(P, (char*)d_ws);
    hipMemsetAsync(d_out, 0, (size_t)out_size * sizeof(float), stream);

    static int lds_set = 0;
    (void)lds_set;
    hipFuncSetAttribute((const void*)tll_main,
                        hipFuncAttributeMaxDynamicSharedMemorySize, 161024);
    tll_main<<<256, 512, 161024, stream>>>(P, b3, (const char*)d_ws,
                                           (unsigned int*)d_out);
}